// Round 1
// baseline (164.151 us; speedup 1.0000x reference)
//
#include <hip/hip_runtime.h>
#include <math.h>

// Problem: RoutingCapsules — B=16, I=2048 in_caps, K=64 in_dim, J=64 num_caps, D=32 dim_caps, 3 routing iters.
// Key identity: u_hat[b,j,i,d] = sum_k W[j,d,k] x[b,i,k] is never materialized.
//   s[b,j,d]  = sum_k W[j,d,k] * y[b,j,k],   y[b,j,k]  = sum_i c[b,j,i] x[b,i,k]
//   uv[b,j,i] = sum_k x[b,i,k] * wv[b,j,k],  wv[b,j,k] = sum_d W[j,d,k] v[b,j,d]
// Iter 1 has uniform c=1/64 -> y1[b,j,k] = ybar[b,k] (j-independent).

#define BB 16
#define II 2048
#define KK 64
#define JJ 64
#define DD 32
#define ITILE 64
#define NT (II / ITILE)   // 32

// ---------------------------------------------------------------------------
// ybar[b,k] = (1/64) * sum_i x[b,i,k]   (uniform-softmax first iteration)
// grid (16, 16): block (b, chunk of 128 i). atomicAdd into zeroed ybar.
// ---------------------------------------------------------------------------
__global__ __launch_bounds__(256) void ybar_kernel(const float* __restrict__ x,
                                                   float* __restrict__ ybar) {
    const int b = blockIdx.x;
    const int ch = blockIdx.y;
    const int tid = threadIdx.x;
    const int k = tid & 63;
    const int r = tid >> 6;
    const float* xp = x + ((size_t)b * II + (size_t)ch * 128) * KK + k;
    float acc = 0.f;
    #pragma unroll 8
    for (int i = r; i < 128; i += 4) acc += xp[(size_t)i * KK];
    __shared__ float sm[256];
    sm[tid] = acc;
    __syncthreads();
    if (tid < 64) {
        const float tot = sm[tid] + sm[tid + 64] + sm[tid + 128] + sm[tid + 192];
        atomicAdd(&ybar[b * KK + tid], tot * (1.0f / 64.0f));
    }
}

// ---------------------------------------------------------------------------
// caps kernel: per (b,j): s[d] = sum_k W[j,d,k] y[b,j,k]; v = squash(s);
//   MODE 0: y := ybar (j-independent), write wv
//   MODE 1: y := y buffer, write wv, re-zero y row for next route pass
//   MODE 2: y := y buffer, write squash(s) to out
// grid (16,4); 4 waves/block, each wave owns 4 j's. All LDS is wave-private.
// ---------------------------------------------------------------------------
template <int MODE>
__global__ __launch_bounds__(256) void caps_kernel(const float* __restrict__ W,
                                                   const float* __restrict__ ybar,
                                                   float* __restrict__ y,
                                                   float* __restrict__ wv,
                                                   float* __restrict__ out) {
    const int b = blockIdx.x;
    const int jq = blockIdx.y;
    const int tid = threadIdx.x;
    const int w = tid >> 6;
    const int lane = tid & 63;

    __shared__ float W_sm[4][DD][65];   // +1 pad: s-phase lane=d reads row d conflict-free
    __shared__ float y_sm[4][KK];
    __shared__ float v_sm[4][DD];

    if (MODE == 0) y_sm[w][lane] = ybar[b * KK + lane];

    for (int jj = 0; jj < 4; ++jj) {
        const int j = jq * 16 + w * 4 + jj;
        const float* Wp = W + (size_t)j * DD * KK;
        #pragma unroll
        for (int d = 0; d < DD; ++d) W_sm[w][d][lane] = Wp[d * KK + lane];
        if (MODE != 0) {
            const size_t yoff = ((size_t)b * JJ + j) * KK + lane;
            y_sm[w][lane] = y[yoff];
            if (MODE == 1) y[yoff] = 0.f;   // prep for next route pass's atomics
        }
        __syncthreads();

        float sv = 0.f;
        if (lane < DD) {
            float a = 0.f;
            #pragma unroll
            for (int k = 0; k < KK; ++k) a += W_sm[w][lane][k] * y_sm[w][k];
            sv = a;
        }
        float ps = (lane < DD) ? sv * sv : 0.f;
        #pragma unroll
        for (int m = 1; m < 64; m <<= 1) ps += __shfl_xor(ps, m, 64);
        // squash factor: sq/(1+sq) * 1/(sqrt(sq)+eps)
        const float f = ps / ((1.f + ps) * (sqrtf(ps) + 1e-8f));

        if (MODE == 2) {
            if (lane < DD) out[((size_t)b * JJ + j) * DD + lane] = sv * f;
        } else {
            if (lane < DD) v_sm[w][lane] = sv * f;
        }
        __syncthreads();

        if (MODE != 2) {
            float a = 0.f;
            #pragma unroll
            for (int d = 0; d < DD; ++d) a += W_sm[w][d][lane] * v_sm[w][d];
            wv[((size_t)b * JJ + j) * KK + lane] = a;
        }
        __syncthreads();
    }
}

// ---------------------------------------------------------------------------
// route kernel: per (b, i-tile of 64):
//   uv[i,j] = sum_k x[i,k] wv[j,k]; blog = (FIRST ? uv : blog+uv);
//   c = softmax_j; y[b,j,k] += sum_i c[i,j] x[i,k] (atomics).
// grid (16,32), 256 thr; 4x4 register tiles for both GEMM phases.
// ---------------------------------------------------------------------------
template <bool FIRST>
__global__ __launch_bounds__(256) void route_kernel(const float* __restrict__ x,
                                                    const float* __restrict__ wv,
                                                    float* __restrict__ blog,
                                                    float* __restrict__ y) {
    const int b = blockIdx.x;
    const int t = blockIdx.y;
    const int tid = threadIdx.x;
    const int i0 = t * ITILE;

    __shared__ float x_smT[KK][65];     // [k][i], transposed; +1 pad
    __shared__ float wv_sm[JJ][68];     // [j][k]; stride 68 keeps float4 stores aligned
    __shared__ float uv_sm[ITILE][65];  // [i][j]; +1 pad for softmax row scans

    // stage x tile (transposed) — float4 global reads, scalar LDS transpose stores
    const float4* x4 = (const float4*)(x + ((size_t)b * II + i0) * KK);
    #pragma unroll
    for (int idx = tid; idx < ITILE * KK / 4; idx += 256) {
        const int i = idx >> 4;
        const int kq = idx & 15;
        const float4 v = x4[idx];
        x_smT[kq * 4 + 0][i] = v.x;
        x_smT[kq * 4 + 1][i] = v.y;
        x_smT[kq * 4 + 2][i] = v.z;
        x_smT[kq * 4 + 3][i] = v.w;
    }
    const float4* wv4 = (const float4*)(wv + (size_t)b * JJ * KK);
    #pragma unroll
    for (int idx = tid; idx < JJ * KK / 4; idx += 256) {
        const int j = idx >> 4;
        const int kq = idx & 15;
        *(float4*)&wv_sm[j][kq * 4] = wv4[idx];
    }
    __syncthreads();

    // ---- uv[i][j] = sum_k x[i][k] * wv[j][k], 4i x 4j per thread ----
    {
        const int ti = tid & 15, tj = tid >> 4;
        const int ib = ti * 4, jb = tj * 4;
        float acc[4][4] = {};
        for (int k = 0; k < KK; ++k) {
            float xv[4], wvv[4];
            #pragma unroll
            for (int c = 0; c < 4; ++c) xv[c] = x_smT[k][ib + c];
            #pragma unroll
            for (int r = 0; r < 4; ++r) wvv[r] = wv_sm[jb + r][k];
            #pragma unroll
            for (int c = 0; c < 4; ++c)
                #pragma unroll
                for (int r = 0; r < 4; ++r)
                    acc[c][r] += xv[c] * wvv[r];
        }
        #pragma unroll
        for (int c = 0; c < 4; ++c)
            #pragma unroll
            for (int r = 0; r < 4; ++r)
                uv_sm[ib + c][jb + r] = acc[c][r];
    }
    __syncthreads();

    // ---- blog accumulate + softmax over j (one thread per i row) ----
    if (tid < ITILE) {
        const int i = tid;
        const size_t bbase = (size_t)b * JJ * II + i0 + i;
        float m = -1e30f;
        if (FIRST) {
            for (int j = 0; j < JJ; ++j) {
                const float u = uv_sm[i][j];
                blog[bbase + (size_t)j * II] = u;   // b1 = uv1 (coalesced across lanes=i)
                m = fmaxf(m, u);
            }
        } else {
            for (int j = 0; j < JJ; ++j) {
                const float u = uv_sm[i][j] + blog[bbase + (size_t)j * II];
                uv_sm[i][j] = u;                    // b2 = b1 + uv2 (not needed later; keep in LDS)
                m = fmaxf(m, u);
            }
        }
        float s = 0.f;
        for (int j = 0; j < JJ; ++j) {
            const float e = __expf(uv_sm[i][j] - m);
            uv_sm[i][j] = e;
            s += e;
        }
        const float inv = 1.f / s;
        for (int j = 0; j < JJ; ++j) uv_sm[i][j] *= inv;   // uv_sm now holds c[i][j]
    }
    __syncthreads();

    // ---- y[j][k] += sum_i c[i][j] * x[i][k], 4j x 4k per thread ----
    {
        const int tj = tid & 15, tk = tid >> 4;
        const int jb = tj * 4, kb = tk * 4;
        float acc[4][4] = {};
        for (int i = 0; i < ITILE; ++i) {
            float cv[4], xv[4];
            #pragma unroll
            for (int r = 0; r < 4; ++r) cv[r] = uv_sm[i][jb + r];
            #pragma unroll
            for (int c = 0; c < 4; ++c) xv[c] = x_smT[kb + c][i];
            #pragma unroll
            for (int r = 0; r < 4; ++r)
                #pragma unroll
                for (int c = 0; c < 4; ++c)
                    acc[r][c] += cv[r] * xv[c];
        }
        float* yp = y + (size_t)b * JJ * KK;
        #pragma unroll
        for (int r = 0; r < 4; ++r)
            #pragma unroll
            for (int c = 0; c < 4; ++c)
                atomicAdd(&yp[(jb + r) * KK + kb + c], acc[r][c]);
    }
}

// ---------------------------------------------------------------------------
// Workspace layout (floats): wv[65536] | y[65536] | ybar[1024] | blog[2097152]
// total ~8.5 MB. y+ybar are contiguous -> single memset.
// ---------------------------------------------------------------------------
extern "C" void kernel_launch(void* const* d_in, const int* in_sizes, int n_in,
                              void* d_out, int out_size, void* d_ws, size_t ws_size,
                              hipStream_t stream) {
    const float* x = (const float*)d_in[0];
    const float* W = (const float*)d_in[1];
    float* out = (float*)d_out;
    float* ws = (float*)d_ws;

    float* wv   = ws;             // 65536 floats
    float* y    = ws + 65536;     // 65536 floats
    float* ybar = ws + 131072;    // 1024 floats
    float* blog = ws + 132096;    // 2097152 floats

    // zero y + ybar (contiguous); ws is poisoned 0xAA each call
    hipMemsetAsync(y, 0, (65536 + 1024) * sizeof(float), stream);

    ybar_kernel<<<dim3(BB, 16), 256, 0, stream>>>(x, ybar);
    caps_kernel<0><<<dim3(BB, 4), 256, 0, stream>>>(W, ybar, y, wv, out);   // v1 -> wv1
    route_kernel<true><<<dim3(BB, NT), 256, 0, stream>>>(x, wv, blog, y);   // b1=uv1, c2, y2
    caps_kernel<1><<<dim3(BB, 4), 256, 0, stream>>>(W, ybar, y, wv, out);   // v2 -> wv2, zero y
    route_kernel<false><<<dim3(BB, NT), 256, 0, stream>>>(x, wv, blog, y);  // b2, c3, y3
    caps_kernel<2><<<dim3(BB, 4), 256, 0, stream>>>(W, ybar, y, wv, out);   // out = squash(s3)
}

// Round 2
// 114.513 us; speedup vs baseline: 1.4335x; 1.4335x over previous
//
#include <hip/hip_runtime.h>
#include <math.h>

// RoutingCapsules — B=16, I=2048, K=64, J=64, D=32, 3 routing iters.
// u_hat[b,j,i,d] = sum_k W[j,d,k] x[b,i,k] is never materialized:
//   s[b,j,d]  = sum_k W[j,d,k] y[b,j,k],    y[b,j,k]  = sum_i c[b,j,i] x[b,i,k]
//   uv[b,j,i] = sum_k x[b,i,k] wv[b,j,k],   wv[b,j,k] = sum_d W[j,d,k] v[b,j,d]
// Iter-1 c is uniform -> y1[b,j,k] = ybar[b,k]  (j-independent).
// Logits are LINEAR in wv:  b2 = uv1+uv2 = x·(wv1+wv2)  -> no logit buffer at all.
// y accumulation: per-i-tile partials (regular stores) + reduction folded into caps,
// replacing 2M device-scope atomicAdds (41 MB write-through in R1 profile).

#define BB 16
#define II 2048
#define KK 64
#define JJ 64
#define DD 32
#define ITILE 64
#define NT (II / ITILE)   // 32 i-tiles
#define YB 16             // ybar partial chunks

// ---------------------------------------------------------------------------
// ybar partials: ybarp[b][q][k] = (1/64) sum_{i in chunk q} x[b,i,k]
// grid (16,16), 256 thr. No atomics, no memset; caps<0> sums the 16 partials.
// ---------------------------------------------------------------------------
__global__ __launch_bounds__(256) void ybar_kernel(const float* __restrict__ x,
                                                   float* __restrict__ ybarp) {
    const int b = blockIdx.x;
    const int q = blockIdx.y;
    const int tid = threadIdx.x;
    const int k = tid & 63;
    const int r = tid >> 6;
    const float* xp = x + ((size_t)b * II + (size_t)q * 128) * KK + k;
    float acc = 0.f;
    #pragma unroll 8
    for (int i = r; i < 128; i += 4) acc += xp[(size_t)i * KK];
    __shared__ float sm[256];
    sm[tid] = acc;
    __syncthreads();
    if (tid < 64)
        ybarp[(b * YB + q) * KK + tid] =
            (sm[tid] + sm[tid + 64] + sm[tid + 128] + sm[tid + 192]) * (1.0f / 64.0f);
}

// ---------------------------------------------------------------------------
// caps kernel: per (b,j): s[d] = sum_k W[j,d,k] y[b,j,k]; v = squash(s);
//   MODE 0: y = sum of ybar partials (j-independent); wv  = W^T v      (wv1)
//   MODE 1: y = sum_t ypart;                          wv += W^T v      (wv1+wv2)
//   MODE 2: y = sum_t ypart;                          out = squash(s)
// grid (16,4); 4 waves/block, each wave owns 4 j. ALL LDS is wave-private ->
// no __syncthreads anywhere.
// ---------------------------------------------------------------------------
template <int MODE>
__global__ __launch_bounds__(256) void caps_kernel(const float* __restrict__ W,
                                                   const float* __restrict__ ybarp,
                                                   const float* __restrict__ ypart,
                                                   float* __restrict__ wv,
                                                   float* __restrict__ out) {
    const int b = blockIdx.x;
    const int jq = blockIdx.y;
    const int tid = threadIdx.x;
    const int w = tid >> 6;
    const int lane = tid & 63;

    __shared__ float W_sm[4][DD][65];   // +1 pad
    __shared__ float y_sm[4][KK];
    __shared__ float v_sm[4][DD];

    if (MODE == 0) {
        const float* yp = ybarp + (size_t)b * YB * KK + lane;
        float a = 0.f;
        #pragma unroll
        for (int t = 0; t < YB; ++t) a += yp[(size_t)t * KK];
        y_sm[w][lane] = a;
    }

    for (int jj = 0; jj < 4; ++jj) {
        const int j = jq * 16 + w * 4 + jj;
        const float* Wp = W + (size_t)j * DD * KK;
        #pragma unroll
        for (int d = 0; d < DD; ++d) W_sm[w][d][lane] = Wp[d * KK + lane];

        if (MODE != 0) {
            const float* pp = ypart + ((size_t)b * NT * JJ + j) * KK + lane;
            float a = 0.f;
            #pragma unroll
            for (int t = 0; t < NT; ++t) a += pp[(size_t)t * JJ * KK];
            y_sm[w][lane] = a;
        }

        float sv = 0.f;
        if (lane < DD) {
            float a = 0.f;
            #pragma unroll
            for (int k = 0; k < KK; ++k) a += W_sm[w][lane][k] * y_sm[w][k];
            sv = a;
        }
        float ps = (lane < DD) ? sv * sv : 0.f;
        #pragma unroll
        for (int m = 1; m < 64; m <<= 1) ps += __shfl_xor(ps, m, 64);
        const float f = ps / ((1.f + ps) * (sqrtf(ps) + 1e-8f));   // squash factor

        if (MODE == 2) {
            if (lane < DD) out[((size_t)b * JJ + j) * DD + lane] = sv * f;
        } else {
            if (lane < DD) v_sm[w][lane] = sv * f;
            float a = 0.f;
            #pragma unroll
            for (int d = 0; d < DD; ++d) a += W_sm[w][d][lane] * v_sm[w][d];
            const size_t idx = ((size_t)b * JJ + j) * KK + lane;
            if (MODE == 1) a += wv[idx];
            wv[idx] = a;
        }
    }
}

// ---------------------------------------------------------------------------
// route kernel (identical for both passes): per (b, i-tile of 64):
//   uv[i,j] = sum_k x[i,k] wv[j,k];  c = softmax_j(uv);
//   ypart[b,t,j,k] = sum_{i in tile} c[i,j] x[i,k]    (regular float4 stores)
// grid (16,32), 256 thr; 4x4 register tiles; softmax parallel across 4 waves.
// ---------------------------------------------------------------------------
__global__ __launch_bounds__(256) void route_kernel(const float* __restrict__ x,
                                                    const float* __restrict__ wv,
                                                    float* __restrict__ ypart) {
    const int b = blockIdx.x;
    const int t = blockIdx.y;
    const int tid = threadIdx.x;
    const int i0 = t * ITILE;

    __shared__ float x_smT[KK][65];     // [k][i] transposed; +1 pad
    __shared__ float wv_sm[JJ][68];     // [j][k]; stride 68 keeps float4 stores aligned
    __shared__ float uv_sm[ITILE][65];  // [i][j] -> later c[i][j]
    __shared__ float red[8][72];        // rows 0-3: per-wave max, rows 4-7: per-wave expsum

    // stage x tile (transposed) — float4 global reads
    const float4* x4 = (const float4*)(x + ((size_t)b * II + i0) * KK);
    #pragma unroll
    for (int idx = tid; idx < ITILE * KK / 4; idx += 256) {
        const int i = idx >> 4;
        const int kq = idx & 15;
        const float4 v = x4[idx];
        x_smT[kq * 4 + 0][i] = v.x;
        x_smT[kq * 4 + 1][i] = v.y;
        x_smT[kq * 4 + 2][i] = v.z;
        x_smT[kq * 4 + 3][i] = v.w;
    }
    const float4* wv4 = (const float4*)(wv + (size_t)b * JJ * KK);
    #pragma unroll
    for (int idx = tid; idx < JJ * KK / 4; idx += 256) {
        *(float4*)&wv_sm[idx >> 4][(idx & 15) * 4] = wv4[idx];
    }
    __syncthreads();

    // ---- uv[i][j] = sum_k x[i][k] wv[j][k], 4i x 4j per thread ----
    {
        const int ib = (tid & 15) * 4, jb = (tid >> 4) * 4;
        float acc[4][4] = {};
        for (int k = 0; k < KK; ++k) {
            float xv[4], wvv[4];
            #pragma unroll
            for (int c = 0; c < 4; ++c) xv[c] = x_smT[k][ib + c];
            #pragma unroll
            for (int r = 0; r < 4; ++r) wvv[r] = wv_sm[jb + r][k];
            #pragma unroll
            for (int c = 0; c < 4; ++c)
                #pragma unroll
                for (int r = 0; r < 4; ++r)
                    acc[c][r] += xv[c] * wvv[r];
        }
        #pragma unroll
        for (int c = 0; c < 4; ++c)
            #pragma unroll
            for (int r = 0; r < 4; ++r)
                uv_sm[ib + c][jb + r] = acc[c][r];
    }
    __syncthreads();

    // ---- softmax over j, parallel: wave w owns j-slice [16w,16w+16) of row i=lane ----
    {
        const int i = tid & 63;
        const int w = tid >> 6;
        const int j0 = w * 16;
        float m = -1e30f;
        #pragma unroll
        for (int jj = 0; jj < 16; ++jj) m = fmaxf(m, uv_sm[i][j0 + jj]);
        red[w][i] = m;
        __syncthreads();
        m = fmaxf(fmaxf(red[0][i], red[1][i]), fmaxf(red[2][i], red[3][i]));
        float s = 0.f;
        #pragma unroll
        for (int jj = 0; jj < 16; ++jj) {
            const float e = __expf(uv_sm[i][j0 + jj] - m);
            uv_sm[i][j0 + jj] = e;
            s += e;
        }
        red[4 + w][i] = s;
        __syncthreads();
        const float inv = 1.f / (red[4][i] + red[5][i] + red[6][i] + red[7][i]);
        #pragma unroll
        for (int jj = 0; jj < 16; ++jj) uv_sm[i][j0 + jj] *= inv;   // now c[i][j]
    }
    __syncthreads();

    // ---- ypart[j][k] = sum_i c[i][j] x[i][k], 4j x 4k per thread, float4 stores ----
    {
        const int jb = (tid & 15) * 4, kb = (tid >> 4) * 4;
        float acc[4][4] = {};
        for (int i = 0; i < ITILE; ++i) {
            float cv[4], xv[4];
            #pragma unroll
            for (int r = 0; r < 4; ++r) cv[r] = uv_sm[i][jb + r];
            #pragma unroll
            for (int c = 0; c < 4; ++c) xv[c] = x_smT[kb + c][i];
            #pragma unroll
            for (int r = 0; r < 4; ++r)
                #pragma unroll
                for (int c = 0; c < 4; ++c)
                    acc[r][c] += cv[r] * xv[c];
        }
        float* yp = ypart + ((size_t)b * NT + t) * JJ * KK;
        #pragma unroll
        for (int r = 0; r < 4; ++r)
            *(float4*)&yp[(jb + r) * KK + kb] =
                make_float4(acc[r][0], acc[r][1], acc[r][2], acc[r][3]);
    }
}

// ---------------------------------------------------------------------------
// Workspace (floats): wv[65536] | ybarp[16384] | ypart[2097152]  (~8.7 MB)
// No memset needed — every buffer is fully written before it is read.
// ---------------------------------------------------------------------------
extern "C" void kernel_launch(void* const* d_in, const int* in_sizes, int n_in,
                              void* d_out, int out_size, void* d_ws, size_t ws_size,
                              hipStream_t stream) {
    const float* x = (const float*)d_in[0];
    const float* W = (const float*)d_in[1];
    float* out = (float*)d_out;
    float* ws = (float*)d_ws;

    float* wv    = ws;                    // 65536
    float* ybarp = ws + 65536;            // 16384
    float* ypart = ws + 65536 + 16384;    // 2097152

    ybar_kernel<<<dim3(BB, YB), 256, 0, stream>>>(x, ybarp);
    caps_kernel<0><<<dim3(BB, 4), 256, 0, stream>>>(W, ybarp, ypart, wv, out);  // wv1
    route_kernel<<<dim3(BB, NT), 256, 0, stream>>>(x, wv, ypart);               // c2 -> y2 partials
    caps_kernel<1><<<dim3(BB, 4), 256, 0, stream>>>(W, ybarp, ypart, wv, out);  // wv = wv1+wv2
    route_kernel<<<dim3(BB, NT), 256, 0, stream>>>(x, wv, ypart);               // c3 -> y3 partials
    caps_kernel<2><<<dim3(BB, 4), 256, 0, stream>>>(W, ybarp, ypart, wv, out);  // out = squash(s3)
}